// Round 6
// baseline (5047.039 us; speedup 1.0000x reference)
//
#include <hip/hip_runtime.h>

// Problem constants: B=8, N=16384, NPOINT=1024, NSAMPLE=32, RADIUS=0.4, C_IN=64
#define R2 0.16f  // f32-nearest of python 0.4*0.4 (== nearest f32 to 0.16)

typedef float f32x2 __attribute__((ext_vector_type(2)));

// Packed IEEE RN add/mul (per-component identical to scalar v_add/v_mul) —
// selection logic stays bit-exact vs the reference while halving VALU instrs.
__device__ __forceinline__ f32x2 pk_add(f32x2 a, f32x2 b) {
  f32x2 d;
  asm("v_pk_add_f32 %0, %1, %2" : "=v"(d) : "v"(a), "v"(b));
  return d;
}
__device__ __forceinline__ f32x2 pk_mul(f32x2 a, f32x2 b) {
  f32x2 d;
  asm("v_pk_mul_f32 %0, %1, %2" : "=v"(d) : "v"(a), "v"(b));
  return d;
}

// Exact (non-contracted) squared distance for ball query.
__device__ __forceinline__ float sqd(float x, float y, float z,
                                     float px, float py, float pz) {
  float dx = __fsub_rn(x, px);
  float dy = __fsub_rn(y, py);
  float dz = __fsub_rn(z, pz);
  return __fadd_rn(__fadd_rn(__fmul_rn(dx, dx), __fmul_rn(dy, dy)),
                   __fmul_rn(dz, dz));
}

// ---------------- FPS: 8 blocks x 256 threads per batch (64 blocks) ----------
// Cross-block per-iteration sync via device-scope atomics in d_ws:
//   publish: relaxed store of packed key, release fetch_add on batch counter
//   consume: relaxed spin until cnt >= 8*it, acquire load, read 8 partials.
// Key = (val_bits<<32) | (16383-idx): u64 max == (max val, min idx on tie) —
// exact argmax semantics (distances >= 0 so float bits are monotone).
// Slot double-buffer needs no reset: block g overwrites part[slot][g] for
// iteration it+2 only after observing cnt>=8*(it+1), which requires every
// block to have incremented for it+1, which happens after each consumed
// iteration it's partials. Counter is zeroed each launch by fps_init.
// blockIdx = g*8 + b keeps a batch's 8 blocks on one XCD (round-robin
// dispatch heuristic — speed only; agent scope keeps it correct anywhere).
__global__ __launch_bounds__(256) void fps_init(unsigned int* __restrict__ cnt) {
  cnt[threadIdx.x] = 0u;  // zero the whole 1 KB counter area
}

__global__ __launch_bounds__(256) void fps_kernel(
    const float* __restrict__ xyz, int* __restrict__ idx_out,
    unsigned int* __restrict__ cnt, unsigned long long* __restrict__ part) {
  int bid = blockIdx.x;
  int b = bid & 7;   // batch
  int g = bid >> 3;  // group within batch, 0..7
  int tid = threadIdx.x;
  const float* xb = xyz + (size_t)b * 16384 * 3;
  int gbase = g << 11;  // 2048 points per block
  // pair q holds points glo = gbase + q*512 + tid (k=2q) and glo+256 (k=2q+1);
  // ascending q/component => ascending global index (tie-break order).
  f32x2 X[4], Y[4], Z[4], M[4];
#pragma unroll
  for (int q = 0; q < 4; ++q) {
    int g0 = gbase + (q << 9) + tid;
    int g1 = g0 + 256;
    X[q] = {xb[g0 * 3 + 0], xb[g1 * 3 + 0]};
    Y[q] = {xb[g0 * 3 + 1], xb[g1 * 3 + 1]};
    Z[q] = {xb[g0 * 3 + 2], xb[g1 * 3 + 2]};
    M[q] = {__builtin_inff(), __builtin_inff()};
  }
  __shared__ float s_val[4];
  __shared__ int s_widx[2];
  if (tid == 0) {
    if (g == 0) idx_out[b * 1024] = 0;
    s_widx[0] = 0x7fffffff;
    s_widx[1] = 0x7fffffff;
  }
  __syncthreads();
  int lane = tid & 63, wid = tid >> 6;
  unsigned int* mycnt = cnt + b * 32;               // 128B stride per batch
  unsigned long long* mypart = part + b * 16;       // [slot][g] = slot*8+g
  float px = xb[0], py = xb[1], pz = xb[2];
  for (int it = 1; it < 1024; ++it) {
    int slot = it & 1;
    // ---- packed sweep (bit-exact vs reference scalar arithmetic)
    f32x2 npx = {-px, -px}, npy = {-py, -py}, npz = {-pz, -pz};
    float tv = -1.0f;
#pragma unroll
    for (int q = 0; q < 4; ++q) {
      f32x2 dx = pk_add(X[q], npx);
      f32x2 dy = pk_add(Y[q], npy);
      f32x2 dz = pk_add(Z[q], npz);
      f32x2 d = pk_add(pk_add(pk_mul(dx, dx), pk_mul(dy, dy)), pk_mul(dz, dz));
      M[q].x = fminf(M[q].x, d.x);
      M[q].y = fminf(M[q].y, d.y);
      tv = fmaxf(fmaxf(tv, M[q].x), M[q].y);  // fuses to v_max3
    }
    // ---- wave butterfly (value only)
    float bv = tv;
#pragma unroll
    for (int off = 32; off; off >>= 1) bv = fmaxf(bv, __shfl_xor(bv, off));
    if (lane == 0) s_val[wid] = bv;
    __syncthreads();  // bar1: 4 wave partials visible
    if (tid == 0) s_widx[slot ^ 1] = 0x7fffffff;  // recycle other buffer
    float v = s_val[lane & 3];
    v = fmaxf(v, __shfl_xor(v, 1));
    v = fmaxf(v, __shfl_xor(v, 2));
    // ---- index by equality re-scan (rare threads), lowest index wins
    if (tv == v) {
      int gid = -1;
#pragma unroll
      for (int q = 0; q < 4; ++q) {
        if (gid < 0 && M[q].x == v) gid = gbase + (q << 9) + tid;
        if (gid < 0 && M[q].y == v) gid = gbase + (q << 9) + tid + 256;
      }
      atomicMin(&s_widx[slot], gid);
    }
    __syncthreads();  // bar2: block winner ready
    // ---- publish block partial, arrive
    if (tid == 0) {
      unsigned long long key =
          ((unsigned long long)__float_as_uint(v) << 32) |
          (unsigned int)(16383 - s_widx[slot]);
      __hip_atomic_store(&mypart[slot * 8 + g], key, __ATOMIC_RELAXED,
                         __HIP_MEMORY_SCOPE_AGENT);
      __hip_atomic_fetch_add(mycnt, 1u, __ATOMIC_RELEASE,
                             __HIP_MEMORY_SCOPE_AGENT);
    }
    // ---- spin until all 8 blocks of this batch arrived
    unsigned int target = (unsigned int)(it << 3);
    while (__hip_atomic_load(mycnt, __ATOMIC_RELAXED,
                             __HIP_MEMORY_SCOPE_AGENT) < target) {
    }
    (void)__hip_atomic_load(mycnt, __ATOMIC_ACQUIRE, __HIP_MEMORY_SCOPE_AGENT);
    // ---- global winner: lanes read 8 partials, 3-step u64 shfl-max
    unsigned long long key = __hip_atomic_load(
        &mypart[slot * 8 + (lane & 7)], __ATOMIC_RELAXED,
        __HIP_MEMORY_SCOPE_AGENT);
#pragma unroll
    for (int off = 1; off <= 4; off <<= 1) {
      unsigned int lo = (unsigned int)key, hi = (unsigned int)(key >> 32);
      unsigned int olo = __shfl_xor(lo, off), ohi = __shfl_xor(hi, off);
      unsigned long long ok = ((unsigned long long)ohi << 32) | olo;
      if (ok > key) key = ok;
    }
    int j = 16383 - (int)(unsigned int)(key & 0xffffffffULL);
    if (g == 0 && tid == 0) idx_out[b * 1024 + it] = j;
    // uniform address -> cache broadcast
    px = xb[j * 3 + 0];
    py = xb[j * 3 + 1];
    pz = xb[j * 3 + 2];
  }
}

// ---------------- gather new_xyz into d_out[0 .. 24576) ----------------------
__global__ __launch_bounds__(256) void gather_newxyz(const float* __restrict__ xyz,
                                                     const int* __restrict__ idx,
                                                     float* __restrict__ out) {
  int t = blockIdx.x * 256 + threadIdx.x;  // 0..8191 = (b,p)
  int b = t >> 10;
  int i = idx[t];
  const float* src = xyz + ((size_t)b * 16384 + i) * 3;
  float* dst = out + (size_t)t * 3;
  dst[0] = src[0];
  dst[1] = src[1];
  dst[2] = src[2];
}

// ---------------- transpose features (B,64,N) -> (B,N,64) --------------------
__global__ __launch_bounds__(256) void transpose_feats(const float* __restrict__ f,
                                                       float* __restrict__ fT) {
  __shared__ float tile[64][65];
  int b = blockIdx.x >> 8;
  int n0 = (blockIdx.x & 255) << 6;
  int t = threadIdx.x;
  int nn = t & 63, c0 = t >> 6;
#pragma unroll
  for (int r = 0; r < 64; r += 4) {
    int c = c0 + r;
    tile[c][nn] = f[((size_t)b * 64 + c) * 16384 + n0 + nn];
  }
  __syncthreads();
  int cc = t & 63, n1 = t >> 6;
#pragma unroll
  for (int r = 0; r < 64; r += 4) {
    int n = n1 + r;
    fT[((size_t)b * 16384 + n0 + n) * 64 + cc] = tile[cc][n];
  }
}

// ---------------- ball query: one wave per centroid --------------------------
__global__ __launch_bounds__(256) void ballquery_kernel(const float* __restrict__ xyz,
                                                        const float* __restrict__ newxyz,
                                                        int* __restrict__ gidx) {
  int wid = threadIdx.x >> 6, lane = threadIdx.x & 63;
  int cid = blockIdx.x * 4 + wid;  // 0..8191
  int b = cid >> 10;
  const float* xb = xyz + (size_t)b * 16384 * 3;
  float cx = newxyz[cid * 3 + 0];
  float cy = newxyz[cid * 3 + 1];
  float cz = newxyz[cid * 3 + 2];
  int* out = gidx + (size_t)cid * 32;
  int found = 0;
  int first = -1;
  for (int c0 = 0; c0 < 16384; c0 += 64) {
    int g = c0 + lane;
    float xx = xb[g * 3 + 0], yy = xb[g * 3 + 1], zz = xb[g * 3 + 2];
    float d2 = sqd(xx, yy, zz, cx, cy, cz);
    bool inr = (d2 <= R2);
    unsigned long long mask = __ballot(inr);
    if (first < 0 && mask) first = c0 + (int)__builtin_ctzll(mask);
    int pre = __popcll(mask & ((1ull << lane) - 1ull));
    int slot = found + pre;
    if (inr && slot < 32) out[slot] = g;
    found += __popcll(mask);
    if (found >= 32) break;
  }
  for (int s = found + lane; s < 32; s += 64) out[s] = first;
}

// ---------------- fused group + MLP(67->64->64->128) + maxpool ---------------
#define FMA16(BASEPTR)                                                     \
  do {                                                                     \
    const float4* hp_ = (const float4*)(BASEPTR);                          \
    float4 v0 = hp_[0], v1 = hp_[1], v2 = hp_[2], v3 = hp_[3];             \
    float a = acc[s];                                                      \
    a = fmaf(w[0], v0.x, a);  a = fmaf(w[1], v0.y, a);                     \
    a = fmaf(w[2], v0.z, a);  a = fmaf(w[3], v0.w, a);                     \
    a = fmaf(w[4], v1.x, a);  a = fmaf(w[5], v1.y, a);                     \
    a = fmaf(w[6], v1.z, a);  a = fmaf(w[7], v1.w, a);                     \
    a = fmaf(w[8], v2.x, a);  a = fmaf(w[9], v2.y, a);                     \
    a = fmaf(w[10], v2.z, a); a = fmaf(w[11], v2.w, a);                    \
    a = fmaf(w[12], v3.x, a); a = fmaf(w[13], v3.y, a);                    \
    a = fmaf(w[14], v3.z, a); a = fmaf(w[15], v3.w, a);                    \
    acc[s] = a;                                                            \
  } while (0)

__global__ __launch_bounds__(256) void mlp_kernel(
    const float* __restrict__ xyz, const float* __restrict__ feats,
    const float* __restrict__ featsT, const float* __restrict__ newxyz,
    const int* __restrict__ gidx,
    const float* __restrict__ W1, const float* __restrict__ b1,
    const float* __restrict__ W2, const float* __restrict__ b2,
    const float* __restrict__ W3, const float* __restrict__ b3,
    float* __restrict__ out, int useT) {
  __shared__ float buf[4][32 * 68];
  int wid = threadIdx.x >> 6, lane = threadIdx.x & 63;
  int cid = blockIdx.x * 4 + wid;
  int b = cid >> 10, p = cid & 1023;
  float* A = buf[wid];
  const int* gi = gidx + (size_t)cid * 32;
  float cx = newxyz[cid * 3 + 0];
  float cy = newxyz[cid * 3 + 1];
  float cz = newxyz[cid * 3 + 2];

  // ---- stage h0
  if (useT) {
    const float4* fT4 = (const float4*)(featsT + (size_t)b * 16384 * 64);
    for (int t = lane; t < 512; t += 64) {
      int s = t >> 4, q = t & 15;
      int g = gi[s];
      float4 v = fT4[(size_t)g * 16 + q];
      *(float4*)(A + s * 68 + q * 4) = v;
    }
  } else {
    const float* fb = feats + (size_t)b * 64 * 16384;
    for (int t = lane; t < 2048; t += 64) {
      int c = t >> 5, s = t & 31;
      int g = gi[s];
      A[s * 68 + c] = fb[(size_t)c * 16384 + g];
    }
  }
  for (int t = lane; t < 96; t += 64) {
    int s = t / 3, c = t - s * 3;
    int g = gi[s];
    float pv = xyz[((size_t)b * 16384 + g) * 3 + c];
    float cv = (c == 0) ? cx : ((c == 1) ? cy : cz);
    A[s * 68 + 64 + c] = __fsub_rn(pv, cv);
  }
  if (lane < 32) A[lane * 68 + 67] = 0.0f;
  __syncthreads();

  int o = lane;
  float acc[32];

  // ---- L1: 67 -> 64
#pragma unroll
  for (int s = 0; s < 32; ++s) acc[s] = b1[o];
  {
    const float* wr = W1 + o * 67;
    for (int cb = 0; cb < 4; ++cb) {
      float w[16];
#pragma unroll
      for (int q = 0; q < 16; ++q) w[q] = wr[3 + cb * 16 + q];
#pragma unroll
      for (int s = 0; s < 32; ++s) { FMA16(A + s * 68 + cb * 16); }
    }
    float w0 = wr[0], w1 = wr[1], w2 = wr[2];
#pragma unroll
    for (int s = 0; s < 32; ++s) {
      float a = acc[s];
      a = fmaf(w0, A[s * 68 + 64], a);
      a = fmaf(w1, A[s * 68 + 65], a);
      a = fmaf(w2, A[s * 68 + 66], a);
      acc[s] = a;
    }
  }
  __syncthreads();
#pragma unroll
  for (int s = 0; s < 32; ++s) A[s * 64 + o] = fmaxf(acc[s], 0.0f);
  __syncthreads();

  // ---- L2: 64 -> 64
#pragma unroll
  for (int s = 0; s < 32; ++s) acc[s] = b2[o];
  {
    const float* wr = W2 + o * 64;
    for (int cb = 0; cb < 4; ++cb) {
      float w[16];
#pragma unroll
      for (int q = 0; q < 16; ++q) w[q] = wr[cb * 16 + q];
#pragma unroll
      for (int s = 0; s < 32; ++s) { FMA16(A + s * 64 + cb * 16); }
    }
  }
  __syncthreads();
#pragma unroll
  for (int s = 0; s < 32; ++s) A[s * 64 + o] = fmaxf(acc[s], 0.0f);
  __syncthreads();

  // ---- L3: 64 -> 128, fused relu + maxpool over s
  float* outp = out + 24576;
  for (int po = 0; po < 2; ++po) {
    int o2 = lane + (po << 6);
#pragma unroll
    for (int s = 0; s < 32; ++s) acc[s] = b3[o2];
    const float* wr = W3 + o2 * 64;
    for (int cb = 0; cb < 4; ++cb) {
      float w[16];
#pragma unroll
      for (int q = 0; q < 16; ++q) w[q] = wr[cb * 16 + q];
#pragma unroll
      for (int s = 0; s < 32; ++s) { FMA16(A + s * 64 + cb * 16); }
    }
    float mx = 0.0f;  // relu floor
#pragma unroll
    for (int s = 0; s < 32; ++s) mx = fmaxf(mx, acc[s]);
    outp[((size_t)b * 128 + o2) * 1024 + p] = mx;
  }
}

extern "C" void kernel_launch(void* const* d_in, const int* in_sizes, int n_in,
                              void* d_out, int out_size, void* d_ws, size_t ws_size,
                              hipStream_t stream) {
  const float* xyz = (const float*)d_in[0];
  const float* feats = (const float*)d_in[1];
  const float* W1 = (const float*)d_in[2];
  const float* b1 = (const float*)d_in[3];
  const float* W2 = (const float*)d_in[4];
  const float* b2 = (const float*)d_in[5];
  const float* W3 = (const float*)d_in[6];
  const float* b3 = (const float*)d_in[7];
  float* out = (float*)d_out;

  // ws layout: [0,32K) idx | [32K,32K+1M) gidx | 4K sync | featsT (32MB)
  int* idx = (int*)d_ws;
  int* gidx = (int*)((char*)d_ws + 32768);
  char* syncbase = (char*)d_ws + 32768 + 1048576;
  unsigned int* cnt = (unsigned int*)syncbase;                    // 1 KB
  unsigned long long* part = (unsigned long long*)(syncbase + 1024);  // 1 KB
  float* featsT = (float*)(syncbase + 4096);
  size_t needT = 32768 + 1048576 + 4096 + (size_t)8 * 16384 * 64 * sizeof(float);
  int useT = (ws_size >= needT) ? 1 : 0;

  fps_init<<<1, 256, 0, stream>>>(cnt);
  fps_kernel<<<64, 256, 0, stream>>>(xyz, idx, cnt, part);
  gather_newxyz<<<32, 256, 0, stream>>>(xyz, idx, out);
  if (useT) transpose_feats<<<2048, 256, 0, stream>>>(feats, featsT);
  ballquery_kernel<<<2048, 256, 0, stream>>>(xyz, out, gidx);
  mlp_kernel<<<2048, 256, 0, stream>>>(xyz, feats, featsT, out, gidx,
                                       W1, b1, W2, b2, W3, b3, out, useT);
}

// Round 7
// 3284.856 us; speedup vs baseline: 1.5365x; 1.5365x over previous
//
#include <hip/hip_runtime.h>

// Problem constants: B=8, N=16384, NPOINT=1024, NSAMPLE=32, RADIUS=0.4, C_IN=64
#define R2 0.16f  // f32-nearest of python 0.4*0.4 (== nearest f32 to 0.16)

typedef float f32x2 __attribute__((ext_vector_type(2)));

// Packed IEEE RN add/mul (per-component identical to scalar v_add/v_mul) —
// selection logic stays bit-exact vs the reference while halving VALU instrs.
__device__ __forceinline__ f32x2 pk_add(f32x2 a, f32x2 b) {
  f32x2 d;
  asm("v_pk_add_f32 %0, %1, %2" : "=v"(d) : "v"(a), "v"(b));
  return d;
}
__device__ __forceinline__ f32x2 pk_mul(f32x2 a, f32x2 b) {
  f32x2 d;
  asm("v_pk_mul_f32 %0, %1, %2" : "=v"(d) : "v"(a), "v"(b));
  return d;
}

// Exact (non-contracted) squared distance for ball query.
__device__ __forceinline__ float sqd(float x, float y, float z,
                                     float px, float py, float pz) {
  float dx = __fsub_rn(x, px);
  float dy = __fsub_rn(y, py);
  float dz = __fsub_rn(z, pz);
  return __fadd_rn(__fadd_rn(__fmul_rn(dx, dx), __fmul_rn(dy, dy)),
                   __fmul_rn(dz, dz));
}

// ---------------- FPS: one block (512 thr, 8 waves) per batch ----------------
// Contiguous ownership: thread owns points [tid*32, tid*32+32); pair q holds
// (tid*32+2q, tid*32+2q+1). Global index is ascending in (wid, lane, k), so
// lowest-index-on-tie == lowest matching (lane, then k) — ballot+ctz picks the
// wave winner lane, a static descending cndmask chain picks its lowest k and
// that element's coords. One LDS slot per wave: packed u64 key
// (val_bits<<18)|((16383-gid)<<4)|wid  (u64 max == max val, min idx, wid tag)
// plus the candidate coords. ONE barrier; then every wave 3-step u64
// shfl-reduces the 8 keys and reads winner coords from LDS (no global load in
// the loop). Slots are double-buffered by it&1; a slot is rewritten for it+2
// only after all waves passed it+1's barrier, which is after all it-reads.
__global__ __launch_bounds__(512) void fps_kernel(const float* __restrict__ xyz,
                                                  int* __restrict__ idx_out) {
  int b = blockIdx.x;
  int tid = threadIdx.x;
  int lane = tid & 63, wid = tid >> 6;
  const float* xb = xyz + (size_t)b * 16384 * 3;
  int base = tid << 5;
  f32x2 X[16], Y[16], Z[16], M[16];
#pragma unroll
  for (int q = 0; q < 16; ++q) {
    int g0 = base + 2 * q;  // and g0+1
    X[q] = {xb[g0 * 3 + 0], xb[g0 * 3 + 3]};
    Y[q] = {xb[g0 * 3 + 1], xb[g0 * 3 + 4]};
    Z[q] = {xb[g0 * 3 + 2], xb[g0 * 3 + 5]};
    M[q] = {__builtin_inff(), __builtin_inff()};
  }
  __shared__ unsigned long long s_key[2][8];
  __shared__ float s_cd[2][3][8];
  if (tid == 0) idx_out[b * 1024] = 0;
  float px = xb[0], py = xb[1], pz = xb[2];
  for (int it = 1; it < 1024; ++it) {
    int sl = it & 1;
    // ---- packed sweep (bit-exact vs reference scalar arithmetic)
    f32x2 npx = {-px, -px}, npy = {-py, -py}, npz = {-pz, -pz};
    float tv = -1.0f;
#pragma unroll
    for (int q = 0; q < 16; ++q) {
      f32x2 dx = pk_add(X[q], npx);
      f32x2 dy = pk_add(Y[q], npy);
      f32x2 dz = pk_add(Z[q], npz);
      f32x2 d = pk_add(pk_add(pk_mul(dx, dx), pk_mul(dy, dy)), pk_mul(dz, dz));
      M[q].x = fminf(M[q].x, d.x);
      M[q].y = fminf(M[q].y, d.y);
      tv = fmaxf(fmaxf(tv, M[q].x), M[q].y);  // fuses to v_max3
    }
    // ---- wave value butterfly
    float bv = tv;
#pragma unroll
    for (int off = 32; off; off >>= 1) bv = fmaxf(bv, __shfl_xor(bv, off));
    // ---- wave winner lane = lowest matching lane (== lowest gid in wave)
    unsigned long long mk = __ballot(tv == bv);
    int wlane = (int)__builtin_ctzll(mk);
    if (lane == wlane) {
      // lowest k achieving bv, + its coords, via static descending chain
      int k = 0;
      float wx = 0.0f, wy = 0.0f, wz = 0.0f;
#pragma unroll
      for (int q = 15; q >= 0; --q) {
        if (M[q].y == bv) { k = 2 * q + 1; wx = X[q].y; wy = Y[q].y; wz = Z[q].y; }
        if (M[q].x == bv) { k = 2 * q;     wx = X[q].x; wy = Y[q].x; wz = Z[q].x; }
      }
      int gid = base + k;
      s_key[sl][wid] = ((unsigned long long)__float_as_uint(bv) << 18) |
                       ((unsigned long long)(unsigned)(16383 - gid) << 4) |
                       (unsigned)wid;
      s_cd[sl][0][wid] = wx;
      s_cd[sl][1][wid] = wy;
      s_cd[sl][2][wid] = wz;
    }
    __syncthreads();  // the only barrier: slots visible
    // ---- every wave reduces the 8 keys (lanes replicate mod 8)
    unsigned long long key = s_key[sl][lane & 7];
#pragma unroll
    for (int off = 1; off <= 4; off <<= 1) {
      unsigned int lo = (unsigned int)key, hi = (unsigned int)(key >> 32);
      unsigned int olo = __shfl_xor(lo, off), ohi = __shfl_xor(hi, off);
      unsigned long long ok = ((unsigned long long)ohi << 32) | olo;
      if (ok > key) key = ok;
    }
    int w = (int)(key & 15ull);
    int j = 16383 - (int)((key >> 4) & 0x3fffull);
    px = s_cd[sl][0][w];
    py = s_cd[sl][1][w];
    pz = s_cd[sl][2][w];
    if (tid == 0) idx_out[b * 1024 + it] = j;
  }
}

// ---------------- gather new_xyz into d_out[0 .. 24576) ----------------------
__global__ __launch_bounds__(256) void gather_newxyz(const float* __restrict__ xyz,
                                                     const int* __restrict__ idx,
                                                     float* __restrict__ out) {
  int t = blockIdx.x * 256 + threadIdx.x;  // 0..8191 = (b,p)
  int b = t >> 10;
  int i = idx[t];
  const float* src = xyz + ((size_t)b * 16384 + i) * 3;
  float* dst = out + (size_t)t * 3;
  dst[0] = src[0];
  dst[1] = src[1];
  dst[2] = src[2];
}

// ---------------- transpose features (B,64,N) -> (B,N,64) --------------------
__global__ __launch_bounds__(256) void transpose_feats(const float* __restrict__ f,
                                                       float* __restrict__ fT) {
  __shared__ float tile[64][65];
  int b = blockIdx.x >> 8;
  int n0 = (blockIdx.x & 255) << 6;
  int t = threadIdx.x;
  int nn = t & 63, c0 = t >> 6;
#pragma unroll
  for (int r = 0; r < 64; r += 4) {
    int c = c0 + r;
    tile[c][nn] = f[((size_t)b * 64 + c) * 16384 + n0 + nn];
  }
  __syncthreads();
  int cc = t & 63, n1 = t >> 6;
#pragma unroll
  for (int r = 0; r < 64; r += 4) {
    int n = n1 + r;
    fT[((size_t)b * 16384 + n0 + n) * 64 + cc] = tile[cc][n];
  }
}

// ---------------- ball query: one wave per centroid --------------------------
__global__ __launch_bounds__(256) void ballquery_kernel(const float* __restrict__ xyz,
                                                        const float* __restrict__ newxyz,
                                                        int* __restrict__ gidx) {
  int wid = threadIdx.x >> 6, lane = threadIdx.x & 63;
  int cid = blockIdx.x * 4 + wid;  // 0..8191
  int b = cid >> 10;
  const float* xb = xyz + (size_t)b * 16384 * 3;
  float cx = newxyz[cid * 3 + 0];
  float cy = newxyz[cid * 3 + 1];
  float cz = newxyz[cid * 3 + 2];
  int* out = gidx + (size_t)cid * 32;
  int found = 0;
  int first = -1;
  for (int c0 = 0; c0 < 16384; c0 += 64) {
    int g = c0 + lane;
    float xx = xb[g * 3 + 0], yy = xb[g * 3 + 1], zz = xb[g * 3 + 2];
    float d2 = sqd(xx, yy, zz, cx, cy, cz);
    bool inr = (d2 <= R2);
    unsigned long long mask = __ballot(inr);
    if (first < 0 && mask) first = c0 + (int)__builtin_ctzll(mask);
    int pre = __popcll(mask & ((1ull << lane) - 1ull));
    int slot = found + pre;
    if (inr && slot < 32) out[slot] = g;
    found += __popcll(mask);
    if (found >= 32) break;
  }
  for (int s = found + lane; s < 32; s += 64) out[s] = first;
}

// ---------------- fused group + MLP(67->64->64->128) + maxpool ---------------
#define FMA16(BASEPTR)                                                     \
  do {                                                                     \
    const float4* hp_ = (const float4*)(BASEPTR);                          \
    float4 v0 = hp_[0], v1 = hp_[1], v2 = hp_[2], v3 = hp_[3];             \
    float a = acc[s];                                                      \
    a = fmaf(w[0], v0.x, a);  a = fmaf(w[1], v0.y, a);                     \
    a = fmaf(w[2], v0.z, a);  a = fmaf(w[3], v0.w, a);                     \
    a = fmaf(w[4], v1.x, a);  a = fmaf(w[5], v1.y, a);                     \
    a = fmaf(w[6], v1.z, a);  a = fmaf(w[7], v1.w, a);                     \
    a = fmaf(w[8], v2.x, a);  a = fmaf(w[9], v2.y, a);                     \
    a = fmaf(w[10], v2.z, a); a = fmaf(w[11], v2.w, a);                    \
    a = fmaf(w[12], v3.x, a); a = fmaf(w[13], v3.y, a);                    \
    a = fmaf(w[14], v3.z, a); a = fmaf(w[15], v3.w, a);                    \
    acc[s] = a;                                                            \
  } while (0)

__global__ __launch_bounds__(256) void mlp_kernel(
    const float* __restrict__ xyz, const float* __restrict__ feats,
    const float* __restrict__ featsT, const float* __restrict__ newxyz,
    const int* __restrict__ gidx,
    const float* __restrict__ W1, const float* __restrict__ b1,
    const float* __restrict__ W2, const float* __restrict__ b2,
    const float* __restrict__ W3, const float* __restrict__ b3,
    float* __restrict__ out, int useT) {
  __shared__ float buf[4][32 * 68];
  int wid = threadIdx.x >> 6, lane = threadIdx.x & 63;
  int cid = blockIdx.x * 4 + wid;
  int b = cid >> 10, p = cid & 1023;
  float* A = buf[wid];
  const int* gi = gidx + (size_t)cid * 32;
  float cx = newxyz[cid * 3 + 0];
  float cy = newxyz[cid * 3 + 1];
  float cz = newxyz[cid * 3 + 2];

  // ---- stage h0
  if (useT) {
    const float4* fT4 = (const float4*)(featsT + (size_t)b * 16384 * 64);
    for (int t = lane; t < 512; t += 64) {
      int s = t >> 4, q = t & 15;
      int g = gi[s];
      float4 v = fT4[(size_t)g * 16 + q];
      *(float4*)(A + s * 68 + q * 4) = v;
    }
  } else {
    const float* fb = feats + (size_t)b * 64 * 16384;
    for (int t = lane; t < 2048; t += 64) {
      int c = t >> 5, s = t & 31;
      int g = gi[s];
      A[s * 68 + c] = fb[(size_t)c * 16384 + g];
    }
  }
  for (int t = lane; t < 96; t += 64) {
    int s = t / 3, c = t - s * 3;
    int g = gi[s];
    float pv = xyz[((size_t)b * 16384 + g) * 3 + c];
    float cv = (c == 0) ? cx : ((c == 1) ? cy : cz);
    A[s * 68 + 64 + c] = __fsub_rn(pv, cv);
  }
  if (lane < 32) A[lane * 68 + 67] = 0.0f;
  __syncthreads();

  int o = lane;
  float acc[32];

  // ---- L1: 67 -> 64
#pragma unroll
  for (int s = 0; s < 32; ++s) acc[s] = b1[o];
  {
    const float* wr = W1 + o * 67;
    for (int cb = 0; cb < 4; ++cb) {
      float w[16];
#pragma unroll
      for (int q = 0; q < 16; ++q) w[q] = wr[3 + cb * 16 + q];
#pragma unroll
      for (int s = 0; s < 32; ++s) { FMA16(A + s * 68 + cb * 16); }
    }
    float w0 = wr[0], w1 = wr[1], w2 = wr[2];
#pragma unroll
    for (int s = 0; s < 32; ++s) {
      float a = acc[s];
      a = fmaf(w0, A[s * 68 + 64], a);
      a = fmaf(w1, A[s * 68 + 65], a);
      a = fmaf(w2, A[s * 68 + 66], a);
      acc[s] = a;
    }
  }
  __syncthreads();
#pragma unroll
  for (int s = 0; s < 32; ++s) A[s * 64 + o] = fmaxf(acc[s], 0.0f);
  __syncthreads();

  // ---- L2: 64 -> 64
#pragma unroll
  for (int s = 0; s < 32; ++s) acc[s] = b2[o];
  {
    const float* wr = W2 + o * 64;
    for (int cb = 0; cb < 4; ++cb) {
      float w[16];
#pragma unroll
      for (int q = 0; q < 16; ++q) w[q] = wr[cb * 16 + q];
#pragma unroll
      for (int s = 0; s < 32; ++s) { FMA16(A + s * 64 + cb * 16); }
    }
  }
  __syncthreads();
#pragma unroll
  for (int s = 0; s < 32; ++s) A[s * 64 + o] = fmaxf(acc[s], 0.0f);
  __syncthreads();

  // ---- L3: 64 -> 128, fused relu + maxpool over s
  float* outp = out + 24576;
  for (int po = 0; po < 2; ++po) {
    int o2 = lane + (po << 6);
#pragma unroll
    for (int s = 0; s < 32; ++s) acc[s] = b3[o2];
    const float* wr = W3 + o2 * 64;
    for (int cb = 0; cb < 4; ++cb) {
      float w[16];
#pragma unroll
      for (int q = 0; q < 16; ++q) w[q] = wr[cb * 16 + q];
#pragma unroll
      for (int s = 0; s < 32; ++s) { FMA16(A + s * 64 + cb * 16); }
    }
    float mx = 0.0f;  // relu floor
#pragma unroll
    for (int s = 0; s < 32; ++s) mx = fmaxf(mx, acc[s]);
    outp[((size_t)b * 128 + o2) * 1024 + p] = mx;
  }
}

extern "C" void kernel_launch(void* const* d_in, const int* in_sizes, int n_in,
                              void* d_out, int out_size, void* d_ws, size_t ws_size,
                              hipStream_t stream) {
  const float* xyz = (const float*)d_in[0];
  const float* feats = (const float*)d_in[1];
  const float* W1 = (const float*)d_in[2];
  const float* b1 = (const float*)d_in[3];
  const float* W2 = (const float*)d_in[4];
  const float* b2 = (const float*)d_in[5];
  const float* W3 = (const float*)d_in[6];
  const float* b3 = (const float*)d_in[7];
  float* out = (float*)d_out;

  int* idx = (int*)d_ws;                                    // 32 KB
  int* gidx = (int*)((char*)d_ws + 32768);                  // 1 MB
  float* featsT = (float*)((char*)d_ws + 32768 + 1048576);  // 32 MB (optional)
  size_t needT = 32768 + 1048576 + (size_t)8 * 16384 * 64 * sizeof(float);
  int useT = (ws_size >= needT) ? 1 : 0;

  fps_kernel<<<8, 512, 0, stream>>>(xyz, idx);
  gather_newxyz<<<32, 256, 0, stream>>>(xyz, idx, out);
  if (useT) transpose_feats<<<2048, 256, 0, stream>>>(feats, featsT);
  ballquery_kernel<<<2048, 256, 0, stream>>>(xyz, out, gidx);
  mlp_kernel<<<2048, 256, 0, stream>>>(xyz, feats, featsT, out, gidx,
                                       W1, b1, W2, b2, W3, b3, out, useT);
}

// Round 8
// 2486.211 us; speedup vs baseline: 2.0300x; 1.3212x over previous
//
#include <hip/hip_runtime.h>

// Problem constants: B=8, N=16384, NPOINT=1024, NSAMPLE=32, RADIUS=0.4, C_IN=64
#define R2 0.16f  // f32-nearest of python 0.4*0.4 (== nearest f32 to 0.16)

typedef float f32x2 __attribute__((ext_vector_type(2)));

// Packed IEEE RN add/mul (per-component identical to scalar v_add/v_mul) —
// selection logic stays bit-exact vs the reference while halving VALU instrs.
__device__ __forceinline__ f32x2 pk_add(f32x2 a, f32x2 b) {
  f32x2 d;
  asm("v_pk_add_f32 %0, %1, %2" : "=v"(d) : "v"(a), "v"(b));
  return d;
}
__device__ __forceinline__ f32x2 pk_mul(f32x2 a, f32x2 b) {
  f32x2 d;
  asm("v_pk_mul_f32 %0, %1, %2" : "=v"(d) : "v"(a), "v"(b));
  return d;
}

// Exact (non-contracted) squared distance for ball query.
__device__ __forceinline__ float sqd(float x, float y, float z,
                                     float px, float py, float pz) {
  float dx = __fsub_rn(x, px);
  float dy = __fsub_rn(y, py);
  float dz = __fsub_rn(z, pz);
  return __fadd_rn(__fadd_rn(__fmul_rn(dx, dx), __fmul_rn(dy, dy)),
                   __fmul_rn(dz, dz));
}

// ---------------- FPS: one block (1024 thr) per batch, 16 pts/thread ---------
// R5 structure (measured 2146 us): packed sweep, value butterfly, 16 partials
// in LDS, redundant per-wave final reduce, equality re-scan + LDS atomicMin
// (lowest-index tie-break), 2 barriers, uniform global coord load.
// NEW: X/Y/Z pinned in VGPRs via asm register barriers — without the pin the
// compiler rematerializes them as per-iteration global reloads (VGPR=48 in R5,
// below the 64-float working set) costing ~48 VMEM + ~130 addr VALU per
// thread-iter. Pinned: ~80 VGPR, still 16 waves/CU at launch_bounds(1024).
__global__ __launch_bounds__(1024) void fps_kernel(const float* __restrict__ xyz,
                                                   int* __restrict__ idx_out) {
  int b = blockIdx.x;
  int tid = threadIdx.x;
  const float* xb = xyz + (size_t)b * 16384 * 3;
  // pair q holds global points g0 = tid + 2q*1024 (lo) and g0+1024 (hi)
  f32x2 X[8], Y[8], Z[8], M[8];
#pragma unroll
  for (int q = 0; q < 8; ++q) {
    int g0 = tid + (q << 11);
    int g1 = g0 + 1024;
    X[q] = {xb[g0 * 3 + 0], xb[g1 * 3 + 0]};
    Y[q] = {xb[g0 * 3 + 1], xb[g1 * 3 + 1]};
    Z[q] = {xb[g0 * 3 + 2], xb[g1 * 3 + 2]};
    M[q] = {__builtin_inff(), __builtin_inff()};
  }
  // Register-pin: asm-defined values can't be rematerialized -> forces the
  // coordinate arrays to stay resident in VGPRs across the 1023 iterations.
#pragma unroll
  for (int q = 0; q < 8; ++q) {
    asm volatile("" : "+v"(X[q]));
    asm volatile("" : "+v"(Y[q]));
    asm volatile("" : "+v"(Z[q]));
  }
  __shared__ float s_val[16];
  __shared__ int s_widx[2];
  if (tid == 0) {
    idx_out[b * 1024] = 0;
    s_widx[0] = 0x7fffffff;
    s_widx[1] = 0x7fffffff;
  }
  __syncthreads();
  int lane = tid & 63, wid = tid >> 6;
  float px = xb[0], py = xb[1], pz = xb[2];
  int buf = 1;
  for (int it = 1; it < 1024; ++it) {
    f32x2 npx = {-px, -px}, npy = {-py, -py}, npz = {-pz, -pz};
    float tv = -1.0f;
#pragma unroll
    for (int q = 0; q < 8; ++q) {
      f32x2 dx = pk_add(X[q], npx);
      f32x2 dy = pk_add(Y[q], npy);
      f32x2 dz = pk_add(Z[q], npz);
      f32x2 d = pk_add(pk_add(pk_mul(dx, dx), pk_mul(dy, dy)), pk_mul(dz, dz));
      M[q].x = fminf(M[q].x, d.x);
      M[q].y = fminf(M[q].y, d.y);
      tv = fmaxf(fmaxf(tv, M[q].x), M[q].y);  // fuses to v_max3
    }
    // wave butterfly (value only)
    float bv = tv;
#pragma unroll
    for (int off = 32; off; off >>= 1) bv = fmaxf(bv, __shfl_xor(bv, off));
    if (lane == 0) s_val[wid] = bv;
    __syncthreads();  // bar1: partials visible
    if (tid == 0) s_widx[buf ^ 1] = 0x7fffffff;  // recycle other buffer
    // every wave redundantly reduces the 16 partials (no serial phase)
    float v = s_val[lane & 15];
#pragma unroll
    for (int off = 8; off; off >>= 1) v = fmaxf(v, __shfl_xor(v, off));
    // index: equality re-scan by the (rare) matching thread(s)
    if (tv == v) {
      int gid = -1;
#pragma unroll
      for (int q = 0; q < 8; ++q) {
        if (gid < 0 && M[q].x == v) gid = tid + (q << 11);
        if (gid < 0 && M[q].y == v) gid = tid + (q << 11) + 1024;
      }
      atomicMin(&s_widx[buf], gid);
    }
    __syncthreads();  // bar2: winner index visible
    int j = s_widx[buf];
    if (tid == 0) idx_out[b * 1024 + it] = j;
    // uniform address -> cache broadcast
    px = xb[j * 3 + 0];
    py = xb[j * 3 + 1];
    pz = xb[j * 3 + 2];
    buf ^= 1;
  }
}

// ---------------- gather new_xyz into d_out[0 .. 24576) ----------------------
__global__ __launch_bounds__(256) void gather_newxyz(const float* __restrict__ xyz,
                                                     const int* __restrict__ idx,
                                                     float* __restrict__ out) {
  int t = blockIdx.x * 256 + threadIdx.x;  // 0..8191 = (b,p)
  int b = t >> 10;
  int i = idx[t];
  const float* src = xyz + ((size_t)b * 16384 + i) * 3;
  float* dst = out + (size_t)t * 3;
  dst[0] = src[0];
  dst[1] = src[1];
  dst[2] = src[2];
}

// ---------------- transpose features (B,64,N) -> (B,N,64) --------------------
__global__ __launch_bounds__(256) void transpose_feats(const float* __restrict__ f,
                                                       float* __restrict__ fT) {
  __shared__ float tile[64][65];
  int b = blockIdx.x >> 8;
  int n0 = (blockIdx.x & 255) << 6;
  int t = threadIdx.x;
  int nn = t & 63, c0 = t >> 6;
#pragma unroll
  for (int r = 0; r < 64; r += 4) {
    int c = c0 + r;
    tile[c][nn] = f[((size_t)b * 64 + c) * 16384 + n0 + nn];
  }
  __syncthreads();
  int cc = t & 63, n1 = t >> 6;
#pragma unroll
  for (int r = 0; r < 64; r += 4) {
    int n = n1 + r;
    fT[((size_t)b * 16384 + n0 + n) * 64 + cc] = tile[cc][n];
  }
}

// ---------------- ball query: one wave per centroid --------------------------
__global__ __launch_bounds__(256) void ballquery_kernel(const float* __restrict__ xyz,
                                                        const float* __restrict__ newxyz,
                                                        int* __restrict__ gidx) {
  int wid = threadIdx.x >> 6, lane = threadIdx.x & 63;
  int cid = blockIdx.x * 4 + wid;  // 0..8191
  int b = cid >> 10;
  const float* xb = xyz + (size_t)b * 16384 * 3;
  float cx = newxyz[cid * 3 + 0];
  float cy = newxyz[cid * 3 + 1];
  float cz = newxyz[cid * 3 + 2];
  int* out = gidx + (size_t)cid * 32;
  int found = 0;
  int first = -1;
  for (int c0 = 0; c0 < 16384; c0 += 64) {
    int g = c0 + lane;
    float xx = xb[g * 3 + 0], yy = xb[g * 3 + 1], zz = xb[g * 3 + 2];
    float d2 = sqd(xx, yy, zz, cx, cy, cz);
    bool inr = (d2 <= R2);
    unsigned long long mask = __ballot(inr);
    if (first < 0 && mask) first = c0 + (int)__builtin_ctzll(mask);
    int pre = __popcll(mask & ((1ull << lane) - 1ull));
    int slot = found + pre;
    if (inr && slot < 32) out[slot] = g;
    found += __popcll(mask);
    if (found >= 32) break;
  }
  for (int s = found + lane; s < 32; s += 64) out[s] = first;
}

// ---------------- fused group + MLP(67->64->64->128) + maxpool ---------------
#define FMA16(BASEPTR)                                                     \
  do {                                                                     \
    const float4* hp_ = (const float4*)(BASEPTR);                          \
    float4 v0 = hp_[0], v1 = hp_[1], v2 = hp_[2], v3 = hp_[3];             \
    float a = acc[s];                                                      \
    a = fmaf(w[0], v0.x, a);  a = fmaf(w[1], v0.y, a);                     \
    a = fmaf(w[2], v0.z, a);  a = fmaf(w[3], v0.w, a);                     \
    a = fmaf(w[4], v1.x, a);  a = fmaf(w[5], v1.y, a);                     \
    a = fmaf(w[6], v1.z, a);  a = fmaf(w[7], v1.w, a);                     \
    a = fmaf(w[8], v2.x, a);  a = fmaf(w[9], v2.y, a);                     \
    a = fmaf(w[10], v2.z, a); a = fmaf(w[11], v2.w, a);                    \
    a = fmaf(w[12], v3.x, a); a = fmaf(w[13], v3.y, a);                    \
    a = fmaf(w[14], v3.z, a); a = fmaf(w[15], v3.w, a);                    \
    acc[s] = a;                                                            \
  } while (0)

__global__ __launch_bounds__(256) void mlp_kernel(
    const float* __restrict__ xyz, const float* __restrict__ feats,
    const float* __restrict__ featsT, const float* __restrict__ newxyz,
    const int* __restrict__ gidx,
    const float* __restrict__ W1, const float* __restrict__ b1,
    const float* __restrict__ W2, const float* __restrict__ b2,
    const float* __restrict__ W3, const float* __restrict__ b3,
    float* __restrict__ out, int useT) {
  __shared__ float buf[4][32 * 68];
  int wid = threadIdx.x >> 6, lane = threadIdx.x & 63;
  int cid = blockIdx.x * 4 + wid;
  int b = cid >> 10, p = cid & 1023;
  float* A = buf[wid];
  const int* gi = gidx + (size_t)cid * 32;
  float cx = newxyz[cid * 3 + 0];
  float cy = newxyz[cid * 3 + 1];
  float cz = newxyz[cid * 3 + 2];

  // ---- stage h0
  if (useT) {
    const float4* fT4 = (const float4*)(featsT + (size_t)b * 16384 * 64);
    for (int t = lane; t < 512; t += 64) {
      int s = t >> 4, q = t & 15;
      int g = gi[s];
      float4 v = fT4[(size_t)g * 16 + q];
      *(float4*)(A + s * 68 + q * 4) = v;
    }
  } else {
    const float* fb = feats + (size_t)b * 64 * 16384;
    for (int t = lane; t < 2048; t += 64) {
      int c = t >> 5, s = t & 31;
      int g = gi[s];
      A[s * 68 + c] = fb[(size_t)c * 16384 + g];
    }
  }
  for (int t = lane; t < 96; t += 64) {
    int s = t / 3, c = t - s * 3;
    int g = gi[s];
    float pv = xyz[((size_t)b * 16384 + g) * 3 + c];
    float cv = (c == 0) ? cx : ((c == 1) ? cy : cz);
    A[s * 68 + 64 + c] = __fsub_rn(pv, cv);
  }
  if (lane < 32) A[lane * 68 + 67] = 0.0f;
  __syncthreads();

  int o = lane;
  float acc[32];

  // ---- L1: 67 -> 64
#pragma unroll
  for (int s = 0; s < 32; ++s) acc[s] = b1[o];
  {
    const float* wr = W1 + o * 67;
    for (int cb = 0; cb < 4; ++cb) {
      float w[16];
#pragma unroll
      for (int q = 0; q < 16; ++q) w[q] = wr[3 + cb * 16 + q];
#pragma unroll
      for (int s = 0; s < 32; ++s) { FMA16(A + s * 68 + cb * 16); }
    }
    float w0 = wr[0], w1 = wr[1], w2 = wr[2];
#pragma unroll
    for (int s = 0; s < 32; ++s) {
      float a = acc[s];
      a = fmaf(w0, A[s * 68 + 64], a);
      a = fmaf(w1, A[s * 68 + 65], a);
      a = fmaf(w2, A[s * 68 + 66], a);
      acc[s] = a;
    }
  }
  __syncthreads();
#pragma unroll
  for (int s = 0; s < 32; ++s) A[s * 64 + o] = fmaxf(acc[s], 0.0f);
  __syncthreads();

  // ---- L2: 64 -> 64
#pragma unroll
  for (int s = 0; s < 32; ++s) acc[s] = b2[o];
  {
    const float* wr = W2 + o * 64;
    for (int cb = 0; cb < 4; ++cb) {
      float w[16];
#pragma unroll
      for (int q = 0; q < 16; ++q) w[q] = wr[cb * 16 + q];
#pragma unroll
      for (int s = 0; s < 32; ++s) { FMA16(A + s * 64 + cb * 16); }
    }
  }
  __syncthreads();
#pragma unroll
  for (int s = 0; s < 32; ++s) A[s * 64 + o] = fmaxf(acc[s], 0.0f);
  __syncthreads();

  // ---- L3: 64 -> 128, fused relu + maxpool over s
  float* outp = out + 24576;
  for (int po = 0; po < 2; ++po) {
    int o2 = lane + (po << 6);
#pragma unroll
    for (int s = 0; s < 32; ++s) acc[s] = b3[o2];
    const float* wr = W3 + o2 * 64;
    for (int cb = 0; cb < 4; ++cb) {
      float w[16];
#pragma unroll
      for (int q = 0; q < 16; ++q) w[q] = wr[cb * 16 + q];
#pragma unroll
      for (int s = 0; s < 32; ++s) { FMA16(A + s * 64 + cb * 16); }
    }
    float mx = 0.0f;  // relu floor
#pragma unroll
    for (int s = 0; s < 32; ++s) mx = fmaxf(mx, acc[s]);
    outp[((size_t)b * 128 + o2) * 1024 + p] = mx;
  }
}

extern "C" void kernel_launch(void* const* d_in, const int* in_sizes, int n_in,
                              void* d_out, int out_size, void* d_ws, size_t ws_size,
                              hipStream_t stream) {
  const float* xyz = (const float*)d_in[0];
  const float* feats = (const float*)d_in[1];
  const float* W1 = (const float*)d_in[2];
  const float* b1 = (const float*)d_in[3];
  const float* W2 = (const float*)d_in[4];
  const float* b2 = (const float*)d_in[5];
  const float* W3 = (const float*)d_in[6];
  const float* b3 = (const float*)d_in[7];
  float* out = (float*)d_out;

  int* idx = (int*)d_ws;                                    // 32 KB
  int* gidx = (int*)((char*)d_ws + 32768);                  // 1 MB
  float* featsT = (float*)((char*)d_ws + 32768 + 1048576);  // 32 MB (optional)
  size_t needT = 32768 + 1048576 + (size_t)8 * 16384 * 64 * sizeof(float);
  int useT = (ws_size >= needT) ? 1 : 0;

  fps_kernel<<<8, 1024, 0, stream>>>(xyz, idx);
  gather_newxyz<<<32, 256, 0, stream>>>(xyz, idx, out);
  if (useT) transpose_feats<<<2048, 256, 0, stream>>>(feats, featsT);
  ballquery_kernel<<<2048, 256, 0, stream>>>(xyz, out, gidx);
  mlp_kernel<<<2048, 256, 0, stream>>>(xyz, feats, featsT, out, gidx,
                                       W1, b1, W2, b2, W3, b3, out, useT);
}